// Round 10
// baseline (293.725 us; speedup 1.0000x reference)
//
#include <hip/hip_runtime.h>
#include <cstddef>

// Problem constants (from reference)
#define NIMG   3
#define NSEQ   64
#define C_TOT  512
#define HH     22
#define WW     22
#define HW     (HH * WW)       // 484 floats per (i,s,c) slice
#define FS     4               // FILTER_SIZE
#define CB     16              // channels per block
#define SCALE  (1.0f/16.0f)    // 1/FEATURE_STRIDE
#define THREADS 256
#define V4_PER_IMG ((CB * HW) / 4)            // 1936 float4 per image-slice
#define FULL_ITERS (V4_PER_IMG / THREADS)     // 7
#define TAIL (V4_PER_IMG - FULL_ITERS * THREADS)  // 144

__device__ __forceinline__ float hat_cdf(float t) {
    if (t <= -1.0f) return 0.0f;
    if (t <= 0.0f)  { float u = t + 1.0f; return 0.5f * u * u; }
    if (t <= 1.0f)  return 0.5f + t - 0.5f * t * t;
    return 1.0f;
}

__global__ __launch_bounds__(256) void prroi_filter_init_kernel(
    const float* __restrict__ feat,   // (NIMG, NSEQ, C, H, W)
    const float* __restrict__ bb,     // (NIMG, NSEQ, 4) as (x,y,w,h)
    float* __restrict__ out)          // (NSEQ, C, FS, FS)
{
    const int s  = blockIdx.x;
    const int c0 = blockIdx.y * CB;

    __shared__ float sXw[NIMG][FS][WW];
    __shared__ float sYc[NIMG][FS][HH];   // y-integrals * coef (area, /NIMG, /(C*FS*FS))
    __shared__ float sFeat[CB * HW];      // one image-slice: 16 ch x 484 = 30976 B
    __shared__ float sOut[CB][FS * FS];

    const int t       = threadIdx.x;
    const int c_local = t >> 4;   // 0..15
    const int sub     = t & 15;   // 0..15

    // ---- coalesced staging: global (contiguous 7744 floats, 16B-aligned) -> regs -> LDS ----
    float4 streg[FULL_ITERS + 1];

    auto STAGE_LOAD = [&](int i) {
        const float4* g = reinterpret_cast<const float4*>(
            feat + (((size_t)i * NSEQ + s) * C_TOT + c0) * HW);
        #pragma unroll
        for (int it = 0; it < FULL_ITERS; ++it)
            streg[it] = g[it * THREADS + t];
        if (t < TAIL) streg[FULL_ITERS] = g[FULL_ITERS * THREADS + t];
    };
    auto STAGE_WRITE = [&]() {
        float4* l4 = reinterpret_cast<float4*>(sFeat);
        #pragma unroll
        for (int it = 0; it < FULL_ITERS; ++it)
            l4[it * THREADS + t] = streg[it];
        if (t < TAIL) l4[FULL_ITERS * THREADS + t] = streg[FULL_ITERS];
    };

    // ---- issue image-0 loads first, compute pooling weights under their latency ----
    STAGE_LOAD(0);

    const int NENT = NIMG * FS * (WW + HH);   // 528
    for (int e = t; e < NENT; e += THREADS) {
        const int i   = e / (FS * (WW + HH));
        const int rem = e % (FS * (WW + HH));
        const int q   = rem / (WW + HH);
        const int k   = rem % (WW + HH);
        const float bx = bb[((size_t)i * NSEQ + s) * 4 + 0] * SCALE;
        const float by = bb[((size_t)i * NSEQ + s) * 4 + 1] * SCALE;
        const float bw = bb[((size_t)i * NSEQ + s) * 4 + 2] * SCALE;
        const float bh = bb[((size_t)i * NSEQ + s) * 4 + 3] * SCALE;
        const float bin_w = bw * (1.0f / FS);
        const float bin_h = bh * (1.0f / FS);
        if (k < WW) {
            const float sx = bx + q * bin_w;
            const float ex = sx + bin_w;
            sXw[i][q][k] = hat_cdf(ex - (float)k) - hat_cdf(sx - (float)k);
        } else {
            const int hh = k - WW;
            const float area = fmaxf(bin_w * bin_h, 0.0f);
            const float coef = (area > 0.0f)
                ? 1.0f / (area * (float)NIMG * (float)(C_TOT * FS * FS))
                : 0.0f;
            const float sy = by + q * bin_h;
            const float ey = sy + bin_h;
            sYc[i][q][hh] = (hat_cdf(ey - (float)hh) - hat_cdf(sy - (float)hh)) * coef;
        }
    }

    STAGE_WRITE();          // compiler inserts vmcnt waits on streg use
    __syncthreads();

    // ---- main: 16 lanes per channel; rows h = sub (+16); feat read from LDS ----
    float acc[FS][FS];
    #pragma unroll
    for (int p = 0; p < FS; ++p)
        #pragma unroll
        for (int q = 0; q < FS; ++q) acc[p][q] = 0.0f;

    auto ROW = [&](int i, int h) {
        const float2* rp = reinterpret_cast<const float2*>(&sFeat[c_local * HW + h * WW]);
        float row[WW];
        #pragma unroll
        for (int j = 0; j < WW / 2; ++j) {
            float2 v = rp[j];
            row[2 * j]     = v.x;
            row[2 * j + 1] = v.y;
        }
        float rpool[FS];
        #pragma unroll
        for (int q = 0; q < FS; ++q) {
            float sum = 0.0f;
            #pragma unroll
            for (int w = 0; w < WW; ++w) sum += sXw[i][q][w] * row[w];
            rpool[q] = sum;
        }
        #pragma unroll
        for (int p = 0; p < FS; ++p) {
            const float yc = sYc[i][p][h];
            #pragma unroll
            for (int q = 0; q < FS; ++q) acc[p][q] += yc * rpool[q];
        }
    };

    #pragma unroll
    for (int i = 0; i < NIMG; ++i) {
        if (i + 1 < NIMG) STAGE_LOAD(i + 1);   // HBM latency hides under compute(i)
        ROW(i, sub);
        if (sub < HH - 16) ROW(i, sub + 16);
        __syncthreads();                        // everyone done reading sFeat
        if (i + 1 < NIMG) { STAGE_WRITE(); __syncthreads(); }
    }

    // ---- reduce across the 16 lanes of each channel group ----
    #pragma unroll
    for (int off = 8; off >= 1; off >>= 1) {
        #pragma unroll
        for (int p = 0; p < FS; ++p)
            #pragma unroll
            for (int q = 0; q < FS; ++q)
                acc[p][q] += __shfl_xor(acc[p][q], off, 64);
    }

    if (sub == 0) {
        #pragma unroll
        for (int p = 0; p < FS; ++p)
            #pragma unroll
            for (int q = 0; q < FS; ++q)
                sOut[c_local][p * FS + q] = acc[p][q];
    }
    __syncthreads();

    out[((size_t)s * C_TOT + c0) * (FS * FS) + t] = sOut[t >> 4][t & 15];
}

extern "C" void kernel_launch(void* const* d_in, const int* in_sizes, int n_in,
                              void* d_out, int out_size, void* d_ws, size_t ws_size,
                              hipStream_t stream) {
    const float* feat = (const float*)d_in[0];   // 3*64*512*22*22
    const float* bb   = (const float*)d_in[1];   // 3*64*4
    float* out        = (float*)d_out;           // 64*512*4*4

    dim3 grid(NSEQ, C_TOT / CB);   // (64, 32)
    dim3 block(THREADS);
    prroi_filter_init_kernel<<<grid, block, 0, stream>>>(feat, bb, out);
}

// Round 14
// 262.615 us; speedup vs baseline: 1.1185x; 1.1185x over previous
//
#include <hip/hip_runtime.h>
#include <cstddef>

// Problem constants (from reference)
#define NIMG   3
#define NSEQ   64
#define C_TOT  512
#define HH     22
#define WW     22
#define HW     (HH * WW)       // 484 floats per (i,s,c) slice
#define FS     4               // FILTER_SIZE
#define CB     16              // channels per block
#define SCALE  (1.0f/16.0f)    // 1/FEATURE_STRIDE
#define THREADS 256
#define V4_PER_IMG ((CB * HW) / 4)            // 1936 float4 per image-slice
#define FULL_ITERS (V4_PER_IMG / THREADS)     // 7
#define TAIL (V4_PER_IMG - FULL_ITERS * THREADS)  // 144

__device__ __forceinline__ float hat_cdf(float t) {
    if (t <= -1.0f) return 0.0f;
    if (t <= 0.0f)  { float u = t + 1.0f; return 0.5f * u * u; }
    if (t <= 1.0f)  return 0.5f + t - 0.5f * t * t;
    return 1.0f;
}

// Direct global->LDS DMA, 16B per lane. LDS dest must be wave-uniform base;
// hardware writes base + lane*16 for active lanes. No VGPR staging -> no spill.
__device__ __forceinline__ void async_copy16(float4* lds_wave_base, const float4* g_lane_src) {
    __builtin_amdgcn_global_load_lds(
        (const __attribute__((address_space(1))) unsigned int*)g_lane_src,
        (__attribute__((address_space(3))) unsigned int*)lds_wave_base,
        16, 0, 0);
}

__global__ __launch_bounds__(256) void prroi_filter_init_kernel(
    const float* __restrict__ feat,   // (NIMG, NSEQ, C, H, W)
    const float* __restrict__ bb,     // (NIMG, NSEQ, 4) as (x,y,w,h)
    float* __restrict__ out)          // (NSEQ, C, FS, FS)
{
    const int s  = blockIdx.x;
    const int c0 = blockIdx.y * CB;

    __shared__ float sXw[NIMG][FS][WW];
    __shared__ float sYc[NIMG][FS][HH];   // y-integrals * coef (area, /NIMG, /(C*FS*FS))
    __shared__ float sFeat[CB * HW];      // one image-slice: 16 ch x 484 = 30976 B
    __shared__ float sOut[CB][FS * FS];

    const int t       = threadIdx.x;
    const int wid     = t >> 6;   // wave 0..3
    const int c_local = t >> 4;   // 0..15
    const int sub     = t & 15;   // 0..15

    // ---- staging: global (contiguous 7744 floats, 16B-aligned) -> LDS via DMA ----
    auto STAGE = [&](int i) {
        const float4* g = reinterpret_cast<const float4*>(
            feat + (((size_t)i * NSEQ + s) * C_TOT + c0) * HW);
        float4* l4 = reinterpret_cast<float4*>(sFeat);
        #pragma unroll
        for (int it = 0; it < FULL_ITERS; ++it)
            async_copy16(&l4[it * THREADS + wid * 64], &g[it * THREADS + t]);
        if (t < TAIL)   // waves 0,1 full; wave 2 lanes 0-15; wave 3 skipped (execz)
            async_copy16(&l4[FULL_ITERS * THREADS + wid * 64], &g[FULL_ITERS * THREADS + t]);
    };

    // ---- issue image-0 DMA first, compute pooling weights under its latency ----
    STAGE(0);

    const int NENT = NIMG * FS * (WW + HH);   // 528
    for (int e = t; e < NENT; e += THREADS) {
        const int i   = e / (FS * (WW + HH));
        const int rem = e % (FS * (WW + HH));
        const int q   = rem / (WW + HH);
        const int k   = rem % (WW + HH);
        const float bx = bb[((size_t)i * NSEQ + s) * 4 + 0] * SCALE;
        const float by = bb[((size_t)i * NSEQ + s) * 4 + 1] * SCALE;
        const float bw = bb[((size_t)i * NSEQ + s) * 4 + 2] * SCALE;
        const float bh = bb[((size_t)i * NSEQ + s) * 4 + 3] * SCALE;
        const float bin_w = bw * (1.0f / FS);
        const float bin_h = bh * (1.0f / FS);
        if (k < WW) {
            const float sx = bx + q * bin_w;
            const float ex = sx + bin_w;
            sXw[i][q][k] = hat_cdf(ex - (float)k) - hat_cdf(sx - (float)k);
        } else {
            const int hh = k - WW;
            const float area = fmaxf(bin_w * bin_h, 0.0f);
            const float coef = (area > 0.0f)
                ? 1.0f / (area * (float)NIMG * (float)(C_TOT * FS * FS))
                : 0.0f;
            const float sy = by + q * bin_h;
            const float ey = sy + bin_h;
            sYc[i][q][hh] = (hat_cdf(ey - (float)hh) - hat_cdf(sy - (float)hh)) * coef;
        }
    }
    __syncthreads();   // drains vmcnt(0): image-0 DMA complete, weights written

    // ---- main: 16 lanes per channel; rows h = sub (+16); feat read from LDS ----
    float acc[FS][FS];
    #pragma unroll
    for (int p = 0; p < FS; ++p)
        #pragma unroll
        for (int q = 0; q < FS; ++q) acc[p][q] = 0.0f;

    auto ROW = [&](int i, int h) {
        const float2* rp = reinterpret_cast<const float2*>(&sFeat[c_local * HW + h * WW]);
        float row[WW];
        #pragma unroll
        for (int j = 0; j < WW / 2; ++j) {
            float2 v = rp[j];
            row[2 * j]     = v.x;
            row[2 * j + 1] = v.y;
        }
        float rpool[FS];
        #pragma unroll
        for (int q = 0; q < FS; ++q) {
            float sum = 0.0f;
            #pragma unroll
            for (int w = 0; w < WW; ++w) sum += sXw[i][q][w] * row[w];
            rpool[q] = sum;
        }
        #pragma unroll
        for (int p = 0; p < FS; ++p) {
            const float yc = sYc[i][p][h];
            #pragma unroll
            for (int q = 0; q < FS; ++q) acc[p][q] += yc * rpool[q];
        }
    };

    #pragma unroll
    for (int i = 0; i < NIMG; ++i) {
        ROW(i, sub);
        if (sub < HH - 16) ROW(i, sub + 16);
        __syncthreads();                         // everyone done reading sFeat
        if (i + 1 < NIMG) {
            STAGE(i + 1);                        // DMA next image-slice
            __syncthreads();                     // drain vmcnt before reads
        }
    }

    // ---- reduce across the 16 lanes of each channel group ----
    #pragma unroll
    for (int off = 8; off >= 1; off >>= 1) {
        #pragma unroll
        for (int p = 0; p < FS; ++p)
            #pragma unroll
            for (int q = 0; q < FS; ++q)
                acc[p][q] += __shfl_xor(acc[p][q], off, 64);
    }

    if (sub == 0) {
        #pragma unroll
        for (int p = 0; p < FS; ++p)
            #pragma unroll
            for (int q = 0; q < FS; ++q)
                sOut[c_local][p * FS + q] = acc[p][q];
    }
    __syncthreads();

    out[((size_t)s * C_TOT + c0) * (FS * FS) + t] = sOut[t >> 4][t & 15];
}

extern "C" void kernel_launch(void* const* d_in, const int* in_sizes, int n_in,
                              void* d_out, int out_size, void* d_ws, size_t ws_size,
                              hipStream_t stream) {
    const float* feat = (const float*)d_in[0];   // 3*64*512*22*22
    const float* bb   = (const float*)d_in[1];   // 3*64*4
    float* out        = (float*)d_out;           // 64*512*4*4

    dim3 grid(NSEQ, C_TOT / CB);   // (64, 32)
    dim3 block(THREADS);
    prroi_filter_init_kernel<<<grid, block, 0, stream>>>(feat, bb, out);
}